// Round 4
// baseline (134.420 us; speedup 1.0000x reference)
//
#include <hip/hip_runtime.h>
#include <hip/hip_bf16.h>

// SimilarityPreserving loss via row-sums only:
//   loss = (1/b^2) * sum_i [ A/sa^2 + B/sb^2 - 2C/(sa*sb) ]
//   A_i = sum_j ct(i,j)^2, B_i = sum_j cs(i,j)^2, C_i = sum_j ct*cs
// ct/cs = cosine grams over row-normalized inputs (bf16 MFMA, fp32 acc).
// Temperature cancels in row-normalization; eps never binds. Sim matrices
// never materialized.
//
// Round-4 gram structure (post-mortem of R3: phases were DMA-latency-bound —
// 16 short phases x exposed L3-latency drain at each barrier):
//  - 512-thread blocks (8 waves, 4 row-groups x 2 col-groups), block strip =
//    256 rows: HALVES total Y DMA (32 strips re-read Y instead of 64) and
//    doubles per-barrier compute while halving per-CU per-phase DMA
//    (1 block/CU stages 32 KB/phase vs R3's 2x32 KB).
//  - grid 256 = exactly 1 block/CU, 64 KB LDS (2 x 32 KB double buffer),
//    8 waves/CU = 2/SIMD. Loop = { barrier; stage(t+1 -> other buf);
//    compute(t) }: DMA has the full ~2k-cyc compute phase to land.
//  - accumulator zero-init folded into normalize_all; gram epilogue uses
//    atomicAdd; finalize reads only 96 KB.

typedef __attribute__((ext_vector_type(8))) short short8;   // 8 bf16 = 4 VGPRs
typedef __attribute__((ext_vector_type(4))) float float4v;  // MFMA C/D

#define BSZ 8192
#define DIM 128
#define NGRP 8    // column groups (1024 cols each)
#define STEPS 16  // 64-col tiles per group

__device__ __forceinline__ void async_ld16(void* lds, const void* g) {
    __builtin_amdgcn_global_load_lds(
        (const __attribute__((address_space(1))) void*)g,
        (__attribute__((address_space(3))) void*)lds, 16, 0, 0);
}

// ---------------------------------------------------------------- normalize
// One wave per row: fp32 norm, write bf16 row-normalized vector.
// Also zero-inits the 3*BSZ accumulator floats (acc = accA|accB|accC).
__global__ __launch_bounds__(256) void normalize_all(
    const float* __restrict__ x0, const float* __restrict__ x1,
    const float* __restrict__ x2, const float* __restrict__ x3,
    __hip_bfloat16* __restrict__ out, float* __restrict__ acc)
{
    int gid = blockIdx.x * 256 + threadIdx.x;
    if (gid < 3 * BSZ) acc[gid] = 0.f;

    int gw   = gid >> 6;           // global wave = row id
    int lane = threadIdx.x & 63;
    int mat  = gw >> 13;           // 0..3
    int row  = gw & (BSZ - 1);
    const float* in = (mat == 0) ? x0 : (mat == 1) ? x1 : (mat == 2) ? x2 : x3;

    const float2* rp = (const float2*)(in + (size_t)row * DIM);
    float2 v = rp[lane];
    float ss = v.x * v.x + v.y * v.y;
    #pragma unroll
    for (int off = 1; off < 64; off <<= 1) ss += __shfl_xor(ss, off);
    float nrm = sqrtf(ss);
    float inv = nrm > 0.f ? 1.f / nrm : 0.f;

    __hip_bfloat162* op = (__hip_bfloat162*)(out + ((size_t)mat * BSZ + row) * DIM);
    __hip_bfloat162 o;
    o.x = __float2bfloat16(v.x * inv);
    o.y = __float2bfloat16(v.y * inv);
    op[lane] = o;
}

// ---------------------------------------------------------------- dual gram
__global__ __launch_bounds__(512, 2) void gram_kernel(
    const __hip_bfloat16* __restrict__ Xs, const __hip_bfloat16* __restrict__ Ys,
    const __hip_bfloat16* __restrict__ Xt, const __hip_bfloat16* __restrict__ Yt,
    float* __restrict__ accA, float* __restrict__ accB, float* __restrict__ accC)
{
    // [buf][mat][chunk]: 64-col x 128-K tile = 1024 16B chunks/mat; 64 KB total
    __shared__ short8 lds[2][2][1024];

    const int tid  = threadIdx.x;
    const int lane = tid & 63;
    const int wave = tid >> 6;    // 0..7
    const int wrow = wave >> 1;   // 0..3 : 64-row group
    const int wcol = wave & 1;    // 0..1 : 32-col half of the 64-col tile
    const int q    = lane >> 4;
    const int l15  = lane & 15;
    const int strip = blockIdx.y;  // 0..31 : rows strip*256 .. +255
    const int grp   = blockIdx.x;  // 0..7  : cols grp*1024 .. +1023

    // A fragments: wave rows strip*256 + wrow*64 + rb*16 + l15 (rb 0..3).
    // MFMA A layout: lane holds A[m=l15][k=q*8+j] -> short8 chunk kk*4+q.
    short8 as[4][4], at[4][4];
    {
        const int rbase = strip * 256 + wrow * 64;
        #pragma unroll
        for (int rb = 0; rb < 4; ++rb) {
            int row = rbase + rb * 16 + l15;
            const short8* xs = (const short8*)(Xs + (size_t)row * DIM);
            const short8* xt = (const short8*)(Xt + (size_t)row * DIM);
            #pragma unroll
            for (int kk = 0; kk < 4; ++kk) {
                as[rb][kk] = xs[kk * 4 + q];
                at[rb][kk] = xt[kk * 4 + q];
            }
        }
    }

    float4v pa[4], pb[4], pc[4];
    #pragma unroll
    for (int rb = 0; rb < 4; ++rb) {
        pa[rb] = (float4v){0.f, 0.f, 0.f, 0.f};
        pb[rb] = pa[rb];
        pc[rb] = pa[rb];
    }

    const short8* gYs = (const short8*)Ys;
    const short8* gYt = (const short8*)Yt;

    // Stage 64-col tile ct into buffer buf. LDS chunk s holds global chunk
    // (row<<4) + (sc ^ (row&7)) — swizzle on the GLOBAL side (LDS side must
    // stay linear for global_load_lds's wave-uniform-base + lane*16).
    auto stage = [&](int buf, int ct) {
        const short8* gs = gYs + (size_t)ct * 1024;
        const short8* gt = gYt + (size_t)ct * 1024;
        #pragma unroll
        for (int it = 0; it < 2; ++it) {
            int s   = it * 512 + tid;     // 0..1023
            int row = s >> 4, sc = s & 15;
            int g   = (row << 4) + (sc ^ (row & 7));
            async_ld16(&lds[buf][0][s], &gs[g]);
            async_ld16(&lds[buf][1][s], &gt[g]);
        }
    };

    stage(0, grp * STEPS);

    for (int t = 0; t < STEPS; ++t) {
        __syncthreads();  // drains DMA(buf t&1) — issued a full compute ago
        if (t + 1 < STEPS) stage((t + 1) & 1, grp * STEPS + t + 1);

        const short8* ls = lds[t & 1][0];
        const short8* lt = lds[t & 1][1];

        #pragma unroll
        for (int cb = 0; cb < 2; ++cb) {
            int col = wcol * 32 + cb * 16 + l15;  // local col 0..63
            short8 bs[4], bt[4];
            #pragma unroll
            for (int kk = 0; kk < 4; ++kk) {
                int chunk = (col << 4) + ((kk * 4 + q) ^ (col & 7));
                bs[kk] = ls[chunk];
                bt[kk] = lt[chunk];
            }
            #pragma unroll
            for (int rb = 0; rb < 4; ++rb) {
                float4v ds = {0.f, 0.f, 0.f, 0.f}, dt = ds;
                #pragma unroll
                for (int kk = 0; kk < 4; ++kk) {
                    ds = __builtin_amdgcn_mfma_f32_16x16x32_bf16(as[rb][kk], bs[kk], ds, 0, 0, 0);
                    dt = __builtin_amdgcn_mfma_f32_16x16x32_bf16(at[rb][kk], bt[kk], dt, 0, 0, 0);
                }
                #pragma unroll
                for (int r = 0; r < 4; ++r) {
                    pa[rb][r] += dt[r] * dt[r];
                    pb[rb][r] += ds[r] * ds[r];
                    pc[rb][r] += dt[r] * ds[r];
                }
            }
        }
    }

    // Epilogue: D row = q*4 + r, col = l15. Reduce over the 16 lanes of each
    // quad-group, then one atomicAdd per row (8-way contention worst case).
    #pragma unroll
    for (int rb = 0; rb < 4; ++rb) {
        #pragma unroll
        for (int r = 0; r < 4; ++r) {
            float va = pa[rb][r], vb = pb[rb][r], vc = pc[rb][r];
            #pragma unroll
            for (int off = 1; off < 16; off <<= 1) {
                va += __shfl_xor(va, off);
                vb += __shfl_xor(vb, off);
                vc += __shfl_xor(vc, off);
            }
            if (l15 == 0) {
                int row = strip * 256 + wrow * 64 + rb * 16 + q * 4 + r;
                atomicAdd(&accA[row], va);
                atomicAdd(&accB[row], vb);
                atomicAdd(&accC[row], vc);
            }
        }
    }
}

// ---------------------------------------------------------------- finalize
__global__ __launch_bounds__(256) void finalize_kernel(
    const float* __restrict__ A, const float* __restrict__ B,
    const float* __restrict__ C, float* __restrict__ out)
{
    __shared__ float red[4];
    float acc = 0.f;
    for (int i = threadIdx.x; i < BSZ; i += 256) {
        float a = A[i], b = B[i], c = C[i];
        float sa = fmaxf(sqrtf(a), 1e-12f);  // NORM_EPS
        float sb = fmaxf(sqrtf(b), 1e-12f);
        acc += a / (sa * sa) + b / (sb * sb) - 2.f * c / (sa * sb);
    }
    #pragma unroll
    for (int off = 1; off < 64; off <<= 1) acc += __shfl_xor(acc, off);
    int wv = threadIdx.x >> 6, lane = threadIdx.x & 63;
    if (lane == 0) red[wv] = acc;
    __syncthreads();
    if (threadIdx.x == 0)
        out[0] = (red[0] + red[1] + red[2] + red[3]) / ((float)BSZ * (float)BSZ);
}

// ---------------------------------------------------------------- launch
extern "C" void kernel_launch(void* const* d_in, const int* in_sizes, int n_in,
                              void* d_out, int out_size, void* d_ws, size_t ws_size,
                              hipStream_t stream) {
    const float* zxs = (const float*)d_in[0];
    const float* zys = (const float*)d_in[1];
    const float* zxt = (const float*)d_in[2];
    const float* zyt = (const float*)d_in[3];
    // d_in[4] = temperature: cancels exactly, unused.
    float* out = (float*)d_out;

    char* ws = (char*)d_ws;
    __hip_bfloat16* nXs = (__hip_bfloat16*)ws;
    __hip_bfloat16* nYs = nXs + (size_t)BSZ * DIM;
    __hip_bfloat16* nXt = nYs + (size_t)BSZ * DIM;
    __hip_bfloat16* nYt = nXt + (size_t)BSZ * DIM;
    float* accA = (float*)(ws + 4 * (size_t)BSZ * DIM * sizeof(__hip_bfloat16));
    float* accB = accA + BSZ;
    float* accC = accB + BSZ;

    // normalize also zero-inits accA..accC (contiguous 3*BSZ floats)
    normalize_all<<<(4 * BSZ) / 4, 256, 0, stream>>>(zxs, zys, zxt, zyt, nXs, accA);

    dim3 grid(NGRP, BSZ / 256);  // 8 x 32 = 256 blocks = 1/CU
    gram_kernel<<<grid, 512, 0, stream>>>(nXs, nYs, nXt, nYt, accA, accB, accC);

    finalize_kernel<<<1, 256, 0, stream>>>(accA, accB, accC, out);
}